// Round 5
// baseline (388.059 us; speedup 1.0000x reference)
//
#include <hip/hip_runtime.h>
#include <hip/hip_bf16.h>
#include <cstdint>

#define DEV __device__ __forceinline__

constexpr int B_   = 2;
constexpr int D_   = 256;
constexpr int CF_  = 768;
constexpr int NTOK = 131072;             // 2*256*256
constexpr int SHIFT = 4;
constexpr int NWIN  = 32;
constexpr float EPS_ = 1e-6f;

typedef short bf16x8 __attribute__((ext_vector_type(8)));
typedef float f32x4  __attribute__((ext_vector_type(4)));

DEV float bf2f(unsigned short u) {
    unsigned v = ((unsigned)u) << 16;
    return __builtin_bit_cast(float, v);
}
DEV unsigned short f2bf(float f) {
    unsigned u = __builtin_bit_cast(unsigned, f);
    unsigned r = (u + 0x7fffu + ((u >> 16) & 1u)) >> 16;
    return (unsigned short)r;
}
DEV float wave_sum(float v) {
    #pragma unroll
    for (int o = 32; o; o >>= 1) v += __shfl_xor(v, o, 64);
    return v;
}

// ---------------- kernel 1: modulation c = silu(cond) @ mod_w.T + mod_b ----------------
__global__ void k_mod(const float* __restrict__ cond, const float* __restrict__ mod_w,
                      const float* __restrict__ mod_b, float* __restrict__ c) {
    int wv = threadIdx.x >> 6, lane = threadIdx.x & 63;
    int idx = blockIdx.x * 4 + wv;
    int b = idx / (3 * D_), j = idx % (3 * D_);
    float acc = 0.f;
    for (int k = lane; k < CF_; k += 64) {
        float cv = cond[b * CF_ + k];
        float s = cv / (1.f + expf(-cv));
        acc += s * mod_w[(size_t)j * CF_ + k];
    }
    acc = wave_sum(acc);
    if (lane == 0) c[b * (3 * D_) + j] = acc + mod_b[j];
}

// ---------------- kernel 2: weights f32 -> bf16 ----------------
__global__ void k_prep_w(const float* __restrict__ qkv_w, const float* __restrict__ out_w,
                         unsigned short* __restrict__ qkvwb, unsigned short* __restrict__ outwb) {
    int i = blockIdx.x * 256 + threadIdx.x;
    const float* src; unsigned short* dst; int off;
    if (i < 49152) { src = qkv_w; dst = qkvwb; off = i * 4; }
    else           { src = out_w; dst = outwb; off = (i - 49152) * 4; }
    float4 v = *(const float4*)(src + off);
    uint2 p;
    p.x = (unsigned)f2bf(v.x) | ((unsigned)f2bf(v.y) << 16);
    p.y = (unsigned)f2bf(v.z) | ((unsigned)f2bf(v.w) << 16);
    *(uint2*)(dst + off) = p;
}

// ---------------- kernel 3: fused RMS+mod staging + QKV GEMM + qk-norm + RoPE ----------------
// One block per 128 tokens. A (=xn bf16) computed from f32 x, staged ONCE into
// padded LDS [128][264]; loop over 6 N-tiles x 8 K-steps with only the 8 KB
// B-tile restaged per step (padded [128][40], reg-staged, loads issued pre-barrier).
__global__ __launch_bounds__(256) void k_qkv_fused(const float* __restrict__ x,
                                                   const float* __restrict__ c,
                                                   const float* __restrict__ norm_scale,
                                                   const unsigned short* __restrict__ wb,
                                                   const float* __restrict__ attn_scale,
                                                   unsigned short* __restrict__ qkv) {
    __shared__ unsigned short As[128 * 264];   // 66 KB, row stride 528 B (2-way banks)
    __shared__ unsigned short Bs[128 * 40];    // 10 KB, row stride 80 B (2-way banks)
    const int t = threadIdx.x, l = t & 63, w = t >> 6;
    const int m0 = blockIdx.x * 128;
    const int bA = m0 >> 16;                   // batch (blocks never cross: 65536%128==0)

    // ---- stage A: xn = x*rinv*(1+sc)*ns + sh, f32 -> bf16, 8 threads per token ----
    {
        const int d0 = (t & 7) * 32;
        #pragma unroll
        for (int p = 0; p < 4; p++) {
            const int trow = p * 32 + (t >> 3);
            const float* xp = x + (size_t)(m0 + trow) * 256 + d0;
            float4 v[8];
            #pragma unroll
            for (int i = 0; i < 8; i++) v[i] = *(const float4*)(xp + i * 4);
            float ss = 0.f;
            #pragma unroll
            for (int i = 0; i < 8; i++)
                ss += v[i].x * v[i].x + v[i].y * v[i].y + v[i].z * v[i].z + v[i].w * v[i].w;
            ss += __shfl_xor(ss, 1, 64);
            ss += __shfl_xor(ss, 2, 64);
            ss += __shfl_xor(ss, 4, 64);
            const float rinv = rsqrtf(ss * (1.f / 256.f) + EPS_);
            #pragma unroll
            for (int i = 0; i < 8; i += 2) {
                float4 sc0 = *(const float4*)(c + bA * 768 + 256 + d0 + i * 4);
                float4 sc1 = *(const float4*)(c + bA * 768 + 256 + d0 + i * 4 + 4);
                float4 sh0 = *(const float4*)(c + bA * 768 + d0 + i * 4);
                float4 sh1 = *(const float4*)(c + bA * 768 + d0 + i * 4 + 4);
                float4 ns0 = *(const float4*)(norm_scale + d0 + i * 4);
                float4 ns1 = *(const float4*)(norm_scale + d0 + i * 4 + 4);
                float y[8] = {
                    v[i].x * rinv * ((1.f + sc0.x) * ns0.x) + sh0.x,
                    v[i].y * rinv * ((1.f + sc0.y) * ns0.y) + sh0.y,
                    v[i].z * rinv * ((1.f + sc0.z) * ns0.z) + sh0.z,
                    v[i].w * rinv * ((1.f + sc0.w) * ns0.w) + sh0.w,
                    v[i+1].x * rinv * ((1.f + sc1.x) * ns1.x) + sh1.x,
                    v[i+1].y * rinv * ((1.f + sc1.y) * ns1.y) + sh1.y,
                    v[i+1].z * rinv * ((1.f + sc1.z) * ns1.z) + sh1.z,
                    v[i+1].w * rinv * ((1.f + sc1.w) * ns1.w) + sh1.w};
                uint4 pk;
                pk.x = (unsigned)f2bf(y[0]) | ((unsigned)f2bf(y[1]) << 16);
                pk.y = (unsigned)f2bf(y[2]) | ((unsigned)f2bf(y[3]) << 16);
                pk.z = (unsigned)f2bf(y[4]) | ((unsigned)f2bf(y[5]) << 16);
                pk.w = (unsigned)f2bf(y[6]) | ((unsigned)f2bf(y[7]) << 16);
                *(uint4*)&As[trow * 264 + d0 + i * 4] = pk;
            }
        }
    }

    const int wm = w >> 1, wn = w & 1;
    const int q16 = l & 15, g = l >> 4;
    const int bcol = t >> 1, bkh = (t & 1) * 16;   // B-stage: 2 threads per col

    for (int nt = 0; nt < 6; nt++) {
        f32x4 acc[4][4] = {};
        for (int k0 = 0; k0 < 8; k0++) {
            // issue B loads early (in flight under previous phase's MFMA drain)
            const unsigned short* wp = wb + (size_t)(nt * 128 + bcol) * 256 + k0 * 32 + bkh;
            uint4 b0 = *(const uint4*)wp;
            uint4 b1 = *(const uint4*)(wp + 8);
            __syncthreads();                     // previous ds_reads of Bs done
            *(uint4*)&Bs[bcol * 40 + bkh]     = b0;
            *(uint4*)&Bs[bcol * 40 + bkh + 8] = b1;
            __syncthreads();
            bf16x8 af[4], bf[4];
            #pragma unroll
            for (int i = 0; i < 4; i++)
                af[i] = *(const bf16x8*)&As[(wm * 64 + i * 16 + q16) * 264 + k0 * 32 + g * 8];
            #pragma unroll
            for (int j = 0; j < 4; j++)
                bf[j] = *(const bf16x8*)&Bs[(wn * 64 + j * 16 + q16) * 40 + g * 8];
            #pragma unroll
            for (int i = 0; i < 4; i++)
                #pragma unroll
                for (int j = 0; j < 4; j++)
                    acc[i][j] = __builtin_amdgcn_mfma_f32_16x16x32_bf16(af[i], bf[j], acc[i][j], 0, 0, 0);
        }

        // ---- epilogue for this n-tile ----
        const int row0 = m0 + wm * 64 + g * 4;
        const int col0 = nt * 128 + wn * 64 + q16;
        if (nt < 4) {
            // q (cols 0-255) or k (cols 256-511): fused L2-norm*sqrt(scale) + RoPE
            const int head = (nt * 2 + wn) & 3;
            const float ssc = sqrtf(attn_scale[head]);
            const float freq = expf(1.14472988584940017f + (float)((q16 & 7) * 4 + head) * 0.07195578545544534f);
            #pragma unroll
            for (int i = 0; i < 4; i++) {
                #pragma unroll
                for (int rg = 0; rg < 4; rg++) {
                    float ss = acc[i][0][rg] * acc[i][0][rg] + acc[i][1][rg] * acc[i][1][rg]
                             + acc[i][2][rg] * acc[i][2][rg] + acc[i][3][rg] * acc[i][3][rg];
                    ss += __shfl_xor(ss, 1, 64);
                    ss += __shfl_xor(ss, 2, 64);
                    ss += __shfl_xor(ss, 4, 64);
                    ss += __shfl_xor(ss, 8, 64);
                    const float rinv = ssc * rsqrtf(ss + EPS_);
                    const int row = row0 + i * 16 + rg;
                    const int oy = (row >> 8) & 255, ox = row & 255;
                    const float ph = -1.f + (float)oy * (2.f / 255.f);
                    const float pw = -1.f + (float)ox * (2.f / 255.f);
                    const float th = ((q16 < 8) ? ph : pw) * freq;
                    const float cs = cosf(th), sn = sinf(th);
                    const float n0v = acc[i][0][rg] * rinv;
                    const float n1v = acc[i][1][rg] * rinv;
                    const float n2v = acc[i][2][rg] * rinv;
                    const float n3v = acc[i][3][rg] * rinv;
                    unsigned short* qp = qkv + (size_t)row * 768 + col0;
                    qp[0]  = f2bf(n0v * cs - n1v * sn);
                    qp[16] = f2bf(n1v * cs + n0v * sn);
                    qp[32] = f2bf(n2v);
                    qp[48] = f2bf(n3v);
                }
            }
        } else {
            #pragma unroll
            for (int i = 0; i < 4; i++)
                #pragma unroll
                for (int j = 0; j < 4; j++) {
                    #pragma unroll
                    for (int rg = 0; rg < 4; rg++)
                        qkv[(size_t)(row0 + i * 16 + rg) * 768 + col0 + j * 16] = f2bf(acc[i][j][rg]);
                }
        }
    }
}

// ---------------- kernel 4: shifted-window attention via MFMA ----------------
__global__ __launch_bounds__(128) void k_attn_mfma(const unsigned short* __restrict__ qkv,
                                                   unsigned short* __restrict__ obuf) {
    __shared__ unsigned short Pl[2][64 * 72];
    __shared__ unsigned short Vt[2][64 * 72];
    __shared__ float Ls[2][64];
    const int w = threadIdx.x >> 6, l = threadIdx.x & 63;
    const int wid = blockIdx.x * 2 + w;
    const int wx = wid & 31, wy = (wid >> 5) & 31, head = (wid >> 10) & 3, b = wid >> 12;
    const int g = l >> 4, q16 = l & 15;

    auto tokof = [&](int p) -> size_t {
        int oy = (wy * 8 + (p >> 3) - SHIFT) & 255;
        int ox = (wx * 8 + (p & 7) - SHIFT) & 255;
        return (size_t)b * 65536 + (size_t)oy * 256 + ox;
    };

    // ---- stage V^T ----
    {
        const unsigned short* vp = qkv + tokof(l) * 768 + 512 + head * 64;
        uint4 vr[8];
        #pragma unroll
        for (int i = 0; i < 8; i++) vr[i] = *(const uint4*)(vp + i * 8);
        #pragma unroll
        for (int i = 0; i < 8; i++) {
            unsigned wd[4] = {vr[i].x, vr[i].y, vr[i].z, vr[i].w};
            #pragma unroll
            for (int cc = 0; cc < 4; cc++) {
                Vt[w][(i * 8 + cc * 2 + 0) * 72 + l] = (unsigned short)(wd[cc] & 0xffff);
                Vt[w][(i * 8 + cc * 2 + 1) * 72 + l] = (unsigned short)(wd[cc] >> 16);
            }
        }
    }

    // ---- K (A) and Q (B) fragments direct from global ----
    bf16x8 af[4][2], bq[4][2];
    #pragma unroll
    for (int i = 0; i < 4; i++) {
        size_t tk = tokof(i * 16 + q16);
        const unsigned short* kp = qkv + tk * 768 + 256 + head * 64 + g * 8;
        af[i][0] = *(const bf16x8*)(kp);
        af[i][1] = *(const bf16x8*)(kp + 32);
        const unsigned short* qp = qkv + tk * 768 + head * 64 + g * 8;
        bq[i][0] = *(const bf16x8*)(qp);
        bq[i][1] = *(const bf16x8*)(qp + 32);
    }

    // ---- S^T = K @ Q^T ----
    f32x4 st[4][4] = {};
    #pragma unroll
    for (int ks = 0; ks < 2; ks++)
        #pragma unroll
        for (int i = 0; i < 4; i++)
            #pragma unroll
            for (int j = 0; j < 4; j++)
                st[i][j] = __builtin_amdgcn_mfma_f32_16x16x32_bf16(af[i][ks], bq[j][ks], st[i][j], 0, 0, 0);

    // ---- boundary-window mask ----
    const bool topw = (wy == 0), leftw = (wx == 0);
    if (topw || leftw) {
        #pragma unroll
        for (int j = 0; j < 4; j++) {
            int query = 16 * j + q16;
            bool qa = ((query >> 3) < 4), qlf = ((query & 7) < 4);
            #pragma unroll
            for (int i = 0; i < 4; i++)
                #pragma unroll
                for (int r = 0; r < 4; r++) {
                    int key = 16 * i + 4 * g + r;
                    bool ok = (!leftw || (qlf == ((key & 7) < 4))) &&
                              (!topw || (qa == ((key >> 3) < 4)));
                    if (!ok) st[i][j][r] = -1e9f;
                }
        }
    }

    // ---- softmax over keys ----
    #pragma unroll
    for (int j = 0; j < 4; j++) {
        float m = -1e30f;
        #pragma unroll
        for (int i = 0; i < 4; i++)
            #pragma unroll
            for (int r = 0; r < 4; r++) m = fmaxf(m, st[i][j][r]);
        m = fmaxf(m, __shfl_xor(m, 16, 64));
        m = fmaxf(m, __shfl_xor(m, 32, 64));
        float s = 0.f;
        #pragma unroll
        for (int i = 0; i < 4; i++)
            #pragma unroll
            for (int r = 0; r < 4; r++) {
                float p = __expf(st[i][j][r] - m);
                st[i][j][r] = p;
                s += p;
            }
        s += __shfl_xor(s, 16, 64);
        s += __shfl_xor(s, 32, 64);
        if (g == 0) Ls[w][16 * j + q16] = s;
        #pragma unroll
        for (int i = 0; i < 4; i++) {
            uint2 pk;
            pk.x = (unsigned)f2bf(st[i][j][0]) | ((unsigned)f2bf(st[i][j][1]) << 16);
            pk.y = (unsigned)f2bf(st[i][j][2]) | ((unsigned)f2bf(st[i][j][3]) << 16);
            *(uint2*)&Pl[w][(16 * j + q16) * 72 + 16 * i + 4 * g] = pk;
        }
    }
    __syncthreads();

    // ---- O = P @ V ----
    f32x4 o[4][4] = {};
    #pragma unroll
    for (int ks = 0; ks < 2; ks++) {
        bf16x8 pa[4], vb[4];
        #pragma unroll
        for (int i = 0; i < 4; i++)
            pa[i] = *(const bf16x8*)&Pl[w][(16 * i + q16) * 72 + ks * 32 + g * 8];
        #pragma unroll
        for (int j = 0; j < 4; j++)
            vb[j] = *(const bf16x8*)&Vt[w][(16 * j + q16) * 72 + ks * 32 + g * 8];
        #pragma unroll
        for (int i = 0; i < 4; i++)
            #pragma unroll
            for (int j = 0; j < 4; j++)
                o[i][j] = __builtin_amdgcn_mfma_f32_16x16x32_bf16(pa[i], vb[j], o[i][j], 0, 0, 0);
    }

    // ---- scale by 1/l and write O ----
    #pragma unroll
    for (int i = 0; i < 4; i++) {
        float4 lv = *(const float4*)&Ls[w][16 * i + 4 * g];
        float lvr[4] = {lv.x, lv.y, lv.z, lv.w};
        #pragma unroll
        for (int r = 0; r < 4; r++) {
            int query = 16 * i + 4 * g + r;
            unsigned short* op = obuf + tokof(query) * 256 + head * 64 + q16;
            float invl = 1.f / lvr[r];
            #pragma unroll
            for (int j = 0; j < 4; j++)
                op[16 * j] = f2bf(o[i][j][r] * invl);
        }
    }
}

// ---------------- kernel 5: out projection via MFMA + gated residual ----------------
__global__ __launch_bounds__(256) void k_out_mfma(const unsigned short* __restrict__ obuf,
                                                  const unsigned short* __restrict__ wb,
                                                  const float* __restrict__ x,
                                                  const float* __restrict__ c,
                                                  float* __restrict__ out) {
    __shared__ unsigned short As[128 * 32];
    __shared__ unsigned short Bs[128 * 32];
    const int t = threadIdx.x, l = t & 63, w = t >> 6;
    const int m0 = blockIdx.x * 128, n0 = blockIdx.y * 128;
    const int wm = w >> 1, wn = w & 1;
    f32x4 acc[4][4] = {};

    const int srow = w * 32 + (l >> 2);
    const int scol = (l & 3) * 8;
    const unsigned short* aA = obuf + (size_t)(m0 + srow) * 256 + scol;
    const unsigned short* aB = wb   + (size_t)(n0 + srow) * 256 + scol;
    unsigned short* dA0 = &As[(w * 2 + 0) * 512];
    unsigned short* dA1 = &As[(w * 2 + 1) * 512];
    unsigned short* dB0 = &Bs[(w * 2 + 0) * 512];
    unsigned short* dB1 = &Bs[(w * 2 + 1) * 512];

    for (int k0 = 0; k0 < 256; k0 += 32) {
        __builtin_amdgcn_global_load_lds((const __attribute__((address_space(1))) void*)(aA + k0),
                                         (__attribute__((address_space(3))) void*)dA0, 16, 0, 0);
        __builtin_amdgcn_global_load_lds((const __attribute__((address_space(1))) void*)(aA + k0 + 16 * 256),
                                         (__attribute__((address_space(3))) void*)dA1, 16, 0, 0);
        __builtin_amdgcn_global_load_lds((const __attribute__((address_space(1))) void*)(aB + k0),
                                         (__attribute__((address_space(3))) void*)dB0, 16, 0, 0);
        __builtin_amdgcn_global_load_lds((const __attribute__((address_space(1))) void*)(aB + k0 + 16 * 256),
                                         (__attribute__((address_space(3))) void*)dB1, 16, 0, 0);
        __syncthreads();
        bf16x8 af[4], bff[4];
        #pragma unroll
        for (int i = 0; i < 4; i++) {
            af[i]  = *(const bf16x8*)&As[(wm * 64 + i * 16 + (l & 15)) * 32 + (l >> 4) * 8];
            bff[i] = *(const bf16x8*)&Bs[(wn * 64 + i * 16 + (l & 15)) * 32 + (l >> 4) * 8];
        }
        #pragma unroll
        for (int i = 0; i < 4; i++)
            #pragma unroll
            for (int j = 0; j < 4; j++)
                acc[i][j] = __builtin_amdgcn_mfma_f32_16x16x32_bf16(af[i], bff[j], acc[i][j], 0, 0, 0);
        __syncthreads();
    }
    const int row0 = m0 + wm * 64 + (l >> 4) * 4;
    const int col0 = n0 + wn * 64 + (l & 15);
    const int b = m0 >> 16;
    #pragma unroll
    for (int j = 0; j < 4; j++) {
        float gg = c[b * 768 + 512 + col0 + j * 16];
        #pragma unroll
        for (int i = 0; i < 4; i++) {
            #pragma unroll
            for (int rg = 0; rg < 4; rg++) {
                int row = row0 + i * 16 + rg, col = col0 + j * 16;
                out[(size_t)row * 256 + col] = x[(size_t)row * 256 + col] + gg * acc[i][j][rg];
            }
        }
    }
}

extern "C" void kernel_launch(void* const* d_in, const int* in_sizes, int n_in,
                              void* d_out, int out_size, void* d_ws, size_t ws_size,
                              hipStream_t stream) {
    const float* x          = (const float*)d_in[0];
    const float* cond       = (const float*)d_in[2];
    const float* norm_scale = (const float*)d_in[3];
    const float* mod_w      = (const float*)d_in[4];
    const float* mod_b      = (const float*)d_in[5];
    const float* qkv_w      = (const float*)d_in[6];
    const float* attn_scale = (const float*)d_in[7];
    const float* out_w      = (const float*)d_in[8];

    char* ws = (char*)d_ws;
    float* c               = (float*)ws;                               // 6 KB
    unsigned short* obuf   = (unsigned short*)(ws + 8192);             // 67 MB
    unsigned short* qkvwb  = (unsigned short*)(ws + 8192 + 67108864);  // 384 KB
    unsigned short* outwb  = (unsigned short*)(ws + 8192 + 67108864 + 393216);   // 128 KB
    unsigned short* qkv    = (unsigned short*)(ws + 8192 + 67108864 + 524288);   // 201 MB
    float* out             = (float*)d_out;

    hipLaunchKernelGGL(k_mod,    dim3(384), dim3(256), 0, stream, cond, mod_w, mod_b, c);
    hipLaunchKernelGGL(k_prep_w, dim3(256), dim3(256), 0, stream, qkv_w, out_w, qkvwb, outwb);
    hipLaunchKernelGGL(k_qkv_fused, dim3(NTOK / 128), dim3(256), 0, stream,
                       x, c, norm_scale, qkvwb, attn_scale, qkv);
    hipLaunchKernelGGL(k_attn_mfma, dim3(2048 * 4 / 2), dim3(128), 0, stream, qkv, obuf);
    hipLaunchKernelGGL(k_out_mfma, dim3(NTOK / 128, 2), dim3(256), 0, stream, obuf, outwb, x, c, out);
}

// Round 6
// 298.843 us; speedup vs baseline: 1.2985x; 1.2985x over previous
//
#include <hip/hip_runtime.h>
#include <hip/hip_bf16.h>
#include <cstdint>

#define DEV __device__ __forceinline__

constexpr int D_   = 256;
constexpr int CF_  = 768;
constexpr int NTOK = 131072;             // 2*256*256
constexpr int SHIFT = 4;
constexpr float EPS_ = 1e-6f;

typedef short bf16x8 __attribute__((ext_vector_type(8)));
typedef float f32x4  __attribute__((ext_vector_type(4)));

DEV float bf2f(unsigned short u) {
    unsigned v = ((unsigned)u) << 16;
    return __builtin_bit_cast(float, v);
}
DEV unsigned short f2bf(float f) {
    unsigned u = __builtin_bit_cast(unsigned, f);
    unsigned r = (u + 0x7fffu + ((u >> 16) & 1u)) >> 16;
    return (unsigned short)r;
}
DEV unsigned cvtpk(float lo, float hi) {      // packed f32->bf16 RNE (no builtin on gfx950)
    unsigned r;
    asm("v_cvt_pk_bf16_f32 %0, %1, %2" : "=v"(r) : "v"(lo), "v"(hi));
    return r;
}
DEV float wave_sum(float v) {
    #pragma unroll
    for (int o = 32; o; o >>= 1) v += __shfl_xor(v, o, 64);
    return v;
}
DEV void gl_lds16(const void* g, void* l) {
    __builtin_amdgcn_global_load_lds(
        (const __attribute__((address_space(1))) void*)g,
        (__attribute__((address_space(3))) void*)l, 16, 0, 0);
}

// ---------------- kernel 1: modulation c = silu(cond) @ mod_w.T + mod_b ----------------
__global__ void k_mod(const float* __restrict__ cond, const float* __restrict__ mod_w,
                      const float* __restrict__ mod_b, float* __restrict__ c) {
    int wv = threadIdx.x >> 6, lane = threadIdx.x & 63;
    int idx = blockIdx.x * 4 + wv;
    int b = idx / (3 * D_), j = idx % (3 * D_);
    float acc = 0.f;
    for (int k = lane; k < CF_; k += 64) {
        float cv = cond[b * CF_ + k];
        float s = cv / (1.f + expf(-cv));
        acc += s * mod_w[(size_t)j * CF_ + k];
    }
    acc = wave_sum(acc);
    if (lane == 0) c[b * (3 * D_) + j] = acc + mod_b[j];
}

// ---------------- kernel 2: merged prep: xn bf16 (RMS+mod) AND weight casts ----------------
__global__ void k_prep(const float* __restrict__ x, const float* __restrict__ c,
                       const float* __restrict__ norm_scale,
                       const float* __restrict__ qkv_w, const float* __restrict__ out_w,
                       unsigned short* __restrict__ xnb,
                       unsigned short* __restrict__ qkvwb, unsigned short* __restrict__ outwb) {
    if (blockIdx.x < 32768) {
        int wv = threadIdx.x >> 6, lane = threadIdx.x & 63;
        int t = blockIdx.x * 4 + wv;
        int b = t >> 16;
        const float* xp = x + (size_t)t * D_ + lane * 4;
        float4 v = *(const float4*)xp;
        float s = v.x * v.x + v.y * v.y + v.z * v.z + v.w * v.w;
        s = wave_sum(s);
        float rinv = rsqrtf(s * (1.f / D_) + EPS_);
        float4 sc = *(const float4*)(c + b * 768 + 256 + lane * 4);
        float4 sh = *(const float4*)(c + b * 768 + lane * 4);
        float4 ns = *(const float4*)(norm_scale + lane * 4);
        float y0 = v.x * rinv * ((1.f + sc.x) * ns.x) + sh.x;
        float y1 = v.y * rinv * ((1.f + sc.y) * ns.y) + sh.y;
        float y2 = v.z * rinv * ((1.f + sc.z) * ns.z) + sh.z;
        float y3 = v.w * rinv * ((1.f + sc.w) * ns.w) + sh.w;
        uint2 p;
        p.x = cvtpk(y0, y1);
        p.y = cvtpk(y2, y3);
        *(uint2*)(xnb + (size_t)t * D_ + lane * 4) = p;
    } else {
        int i = (blockIdx.x - 32768) * 256 + threadIdx.x;
        const float* src; unsigned short* dst; int off;
        if (i < 49152) { src = qkv_w; dst = qkvwb; off = i * 4; }
        else           { src = out_w; dst = outwb; off = (i - 49152) * 4; }
        float4 v = *(const float4*)(src + off);
        uint2 p;
        p.x = cvtpk(v.x, v.y);
        p.y = cvtpk(v.z, v.w);
        *(uint2*)(dst + off) = p;
    }
}

// ---------------- kernel 3: QKV GEMM via MFMA + fused qk-norm + RoPE epilogue ----------------
// Round-4 proven structure. NEW: XCD-chunked, n-tile-innermost grid swizzle so the 6
// column-tiles sharing one 64 KB A-panel run consecutively on the same XCD's L2.
__global__ __launch_bounds__(256) void k_qkv_mfma(const unsigned short* __restrict__ xnb,
                                                  const unsigned short* __restrict__ wb,
                                                  const float* __restrict__ attn_scale,
                                                  unsigned short* __restrict__ qkv) {
    __shared__ unsigned short As[128 * 32];
    __shared__ unsigned short Bs[128 * 32];
    const int t = threadIdx.x, l = t & 63, w = t >> 6;
    const int bid = blockIdx.x;
    const int lid = (bid & 7) * 768 + (bid >> 3);    // 6144 blocks, 8 XCD chunks of 768
    const int m0 = (lid / 6) * 128;
    const int nt = lid % 6;
    const int n0 = nt * 128;
    const int wm = w >> 1, wn = w & 1;
    f32x4 acc[4][4] = {};

    const int srow = w * 32 + (l >> 2);
    const int scol = (l & 3) * 8;
    const unsigned short* aA = xnb + (size_t)(m0 + srow) * 256 + scol;
    const unsigned short* aB = wb  + (size_t)(n0 + srow) * 256 + scol;
    unsigned short* dA0 = &As[(w * 2 + 0) * 512];
    unsigned short* dA1 = &As[(w * 2 + 1) * 512];
    unsigned short* dB0 = &Bs[(w * 2 + 0) * 512];
    unsigned short* dB1 = &Bs[(w * 2 + 1) * 512];

    for (int k0 = 0; k0 < 256; k0 += 32) {
        gl_lds16(aA + k0,             dA0);
        gl_lds16(aA + k0 + 16 * 256,  dA1);
        gl_lds16(aB + k0,             dB0);
        gl_lds16(aB + k0 + 16 * 256,  dB1);
        __syncthreads();
        bf16x8 af[4], bff[4];
        #pragma unroll
        for (int i = 0; i < 4; i++) {
            af[i]  = *(const bf16x8*)&As[(wm * 64 + i * 16 + (l & 15)) * 32 + (l >> 4) * 8];
            bff[i] = *(const bf16x8*)&Bs[(wn * 64 + i * 16 + (l & 15)) * 32 + (l >> 4) * 8];
        }
        #pragma unroll
        for (int i = 0; i < 4; i++)
            #pragma unroll
            for (int j = 0; j < 4; j++)
                acc[i][j] = __builtin_amdgcn_mfma_f32_16x16x32_bf16(af[i], bff[j], acc[i][j], 0, 0, 0);
        __syncthreads();
    }
    const int row0 = m0 + wm * 64 + (l >> 4) * 4;
    const int col0 = n0 + wn * 64 + (l & 15);
    const int q16 = l & 15;

    if (nt < 4) {
        // q (nt=0,1) or k (nt=2,3): fused L2-norm * sqrt(scale) + RoPE
        const int head = (nt * 2 + wn) & 3;
        const float ssc = sqrtf(attn_scale[head]);
        const float freq = expf(1.14472988584940017f + (float)((q16 & 7) * 4 + head) * 0.07195578545544534f);
        #pragma unroll
        for (int i = 0; i < 4; i++) {
            #pragma unroll
            for (int rg = 0; rg < 4; rg++) {
                float ss = acc[i][0][rg] * acc[i][0][rg] + acc[i][1][rg] * acc[i][1][rg]
                         + acc[i][2][rg] * acc[i][2][rg] + acc[i][3][rg] * acc[i][3][rg];
                ss += __shfl_xor(ss, 1, 64);
                ss += __shfl_xor(ss, 2, 64);
                ss += __shfl_xor(ss, 4, 64);
                ss += __shfl_xor(ss, 8, 64);
                const float rinv = ssc * rsqrtf(ss + EPS_);
                const int row = row0 + i * 16 + rg;
                const int oy = (row >> 8) & 255, ox = row & 255;
                const float ph = -1.f + (float)oy * (2.f / 255.f);
                const float pw = -1.f + (float)ox * (2.f / 255.f);
                const float th = ((q16 < 8) ? ph : pw) * freq;
                const float cs = cosf(th), sn = sinf(th);
                const float n0v = acc[i][0][rg] * rinv;
                const float n1v = acc[i][1][rg] * rinv;
                const float n2v = acc[i][2][rg] * rinv;
                const float n3v = acc[i][3][rg] * rinv;
                unsigned short* qp = qkv + (size_t)row * 768 + col0;
                qp[0]  = f2bf(n0v * cs - n1v * sn);
                qp[16] = f2bf(n1v * cs + n0v * sn);
                qp[32] = f2bf(n2v);
                qp[48] = f2bf(n3v);
            }
        }
    } else {
        #pragma unroll
        for (int i = 0; i < 4; i++)
            #pragma unroll
            for (int j = 0; j < 4; j++) {
                #pragma unroll
                for (int rg = 0; rg < 4; rg++)
                    qkv[(size_t)(row0 + i * 16 + rg) * 768 + col0 + j * 16] = f2bf(acc[i][j][rg]);
            }
    }
}

// ---------------- kernel 4: fused window attention + out-projection + gated residual ----
// Block = 1 window, 4 waves = 4 heads. S^T = mfma(K,Q); softmax in-register; P goes
// in-register to PV A-fragments via cvt_pk_bf16 + shfl (no P LDS). V^T staged per wave
// (36.9 KB); after PV the same LDS is reused as the o-stage [64][264] for the out GEMM.
__global__ __launch_bounds__(256) void k_attn_out(const unsigned short* __restrict__ qkv,
                                                  const unsigned short* __restrict__ outwb,
                                                  const float* __restrict__ x,
                                                  const float* __restrict__ c,
                                                  float* __restrict__ out) {
    __shared__ unsigned short Mem[4 * 64 * 72];    // per-wave V^T; reused as ostage[64][264]
    __shared__ float Ls[4][64];
    const int w = threadIdx.x >> 6, l = threadIdx.x & 63;
    const int bid = blockIdx.x;
    const int lid = (bid & 7) * 256 + (bid >> 3);  // XCD-contiguous windows
    const int wx = lid & 31, wy = (lid >> 5) & 31, b = lid >> 10;
    const int head = w;
    const int g = l >> 4, q16 = l & 15;
    unsigned short* Vt = &Mem[w * 4608];

    auto tokof = [&](int p) -> size_t {
        int oy = (wy * 8 + (p >> 3) - SHIFT) & 255;
        int ox = (wx * 8 + (p & 7) - SHIFT) & 255;
        return (size_t)b * 65536 + (size_t)oy * 256 + ox;
    };

    // ---- stage V^T (this wave's head): Vt[d][key] ----
    {
        const unsigned short* vp = qkv + tokof(l) * 768 + 512 + head * 64;
        uint4 vr[8];
        #pragma unroll
        for (int i = 0; i < 8; i++) vr[i] = *(const uint4*)(vp + i * 8);
        #pragma unroll
        for (int i = 0; i < 8; i++) {
            unsigned wd[4] = {vr[i].x, vr[i].y, vr[i].z, vr[i].w};
            #pragma unroll
            for (int cc = 0; cc < 4; cc++) {
                Vt[(i * 8 + cc * 2 + 0) * 72 + l] = (unsigned short)(wd[cc] & 0xffff);
                Vt[(i * 8 + cc * 2 + 1) * 72 + l] = (unsigned short)(wd[cc] >> 16);
            }
        }
    }

    // ---- K (A) and Q (B) fragments direct from global ----
    bf16x8 af[4][2], bq[4][2];
    #pragma unroll
    for (int i = 0; i < 4; i++) {
        size_t tk = tokof(i * 16 + q16);
        const unsigned short* kp = qkv + tk * 768 + 256 + head * 64 + g * 8;
        af[i][0] = *(const bf16x8*)(kp);
        af[i][1] = *(const bf16x8*)(kp + 32);
        const unsigned short* qp = qkv + tk * 768 + head * 64 + g * 8;
        bq[i][0] = *(const bf16x8*)(qp);
        bq[i][1] = *(const bf16x8*)(qp + 32);
    }

    // ---- S^T = K @ Q^T: st[i][j][r] = S[key=16i+4g+r][query=16j+q16] ----
    f32x4 st[4][4] = {};
    #pragma unroll
    for (int ks = 0; ks < 2; ks++)
        #pragma unroll
        for (int i = 0; i < 4; i++)
            #pragma unroll
            for (int j = 0; j < 4; j++)
                st[i][j] = __builtin_amdgcn_mfma_f32_16x16x32_bf16(af[i][ks], bq[j][ks], st[i][j], 0, 0, 0);

    // ---- boundary-window mask ----
    const bool topw = (wy == 0), leftw = (wx == 0);
    if (topw || leftw) {
        #pragma unroll
        for (int j = 0; j < 4; j++) {
            int query = 16 * j + q16;
            bool qa = ((query >> 3) < 4), qlf = ((query & 7) < 4);
            #pragma unroll
            for (int i = 0; i < 4; i++)
                #pragma unroll
                for (int r = 0; r < 4; r++) {
                    int key = 16 * i + 4 * g + r;
                    bool ok = (!leftw || (qlf == ((key & 7) < 4))) &&
                              (!topw || (qa == ((key >> 3) < 4)));
                    if (!ok) st[i][j][r] = -1e9f;
                }
        }
    }

    // ---- softmax over keys (per query col) ----
    #pragma unroll
    for (int j = 0; j < 4; j++) {
        float m = -1e30f;
        #pragma unroll
        for (int i = 0; i < 4; i++)
            #pragma unroll
            for (int r = 0; r < 4; r++) m = fmaxf(m, st[i][j][r]);
        m = fmaxf(m, __shfl_xor(m, 16, 64));
        m = fmaxf(m, __shfl_xor(m, 32, 64));
        float s = 0.f;
        #pragma unroll
        for (int i = 0; i < 4; i++)
            #pragma unroll
            for (int r = 0; r < 4; r++) {
                float p = __expf(st[i][j][r] - m);
                st[i][j][r] = p;
                s += p;
            }
        s += __shfl_xor(s, 16, 64);
        s += __shfl_xor(s, 32, 64);
        if (g == 0) Ls[w][16 * j + q16] = s;
    }
    __syncthreads();    // Vt fully staged (also orders later Mem reuse)

    // ---- PV with in-register P transpose (cvt_pk + shfl; no P LDS) ----
    // Target A-frag word (qb, ks, wd): P[16qb+q16][ks*32+g*8+2wd .. +1]; holder lane
    // = 16*((2(g&1)+(wd>>1))&3)+q16, holder reg = pk[4ks+2(g>>1)+(wd&1)] (2-way select).
    bf16x8 vb[4][2];
    #pragma unroll
    for (int j = 0; j < 4; j++) {
        vb[j][0] = *(const bf16x8*)&Vt[(16 * j + q16) * 72 + g * 8];
        vb[j][1] = *(const bf16x8*)&Vt[(16 * j + q16) * 72 + 32 + g * 8];
    }
    const int ghi = g >> 1;
    const int srcl0 = ((2 * (g & 1)) & 3) * 16 + q16;
    const int srcl1 = ((2 * (g & 1) + 1) & 3) * 16 + q16;
    f32x4 o[4][4] = {};
    #pragma unroll
    for (int qb = 0; qb < 4; qb++) {
        unsigned pk[8];
        #pragma unroll
        for (int ih = 0; ih < 4; ih++) {
            pk[2 * ih]     = cvtpk(st[ih][qb][0], st[ih][qb][1]);
            pk[2 * ih + 1] = cvtpk(st[ih][qb][2], st[ih][qb][3]);
        }
        unsigned pw[8];
        #pragma unroll
        for (int ks = 0; ks < 2; ks++) {
            #pragma unroll
            for (int wd = 0; wd < 4; wd++) {
                const int srcl = (wd < 2) ? srcl0 : srcl1;
                unsigned va  = (unsigned)__shfl((int)pk[4 * ks + (wd & 1)], srcl, 64);
                unsigned vbb = (unsigned)__shfl((int)pk[4 * ks + 2 + (wd & 1)], srcl, 64);
                pw[ks * 4 + wd] = ghi ? vbb : va;
            }
        }
        uint4 paw0 = {pw[0], pw[1], pw[2], pw[3]};
        uint4 paw1 = {pw[4], pw[5], pw[6], pw[7]};
        bf16x8 paA = __builtin_bit_cast(bf16x8, paw0);
        bf16x8 paB = __builtin_bit_cast(bf16x8, paw1);
        #pragma unroll
        for (int j = 0; j < 4; j++) {
            o[qb][j] = __builtin_amdgcn_mfma_f32_16x16x32_bf16(paA, vb[j][0], o[qb][j], 0, 0, 0);
            o[qb][j] = __builtin_amdgcn_mfma_f32_16x16x32_bf16(paB, vb[j][1], o[qb][j], 0, 0, 0);
        }
    }

    // ---- scale by 1/l, stage O bf16 into LDS [64][264] (reusing Vt memory) ----
    __syncthreads();    // all Vt reads done before overwrite
    unsigned short* ost = Mem;
    #pragma unroll
    for (int i = 0; i < 4; i++) {
        float4 lv = *(const float4*)&Ls[w][16 * i + 4 * g];
        float lvr[4] = {lv.x, lv.y, lv.z, lv.w};
        #pragma unroll
        for (int r = 0; r < 4; r++) {
            const float invl = 1.f / lvr[r];
            const int row = 16 * i + 4 * g + r;
            #pragma unroll
            for (int j = 0; j < 4; j++)
                ost[row * 264 + head * 64 + 16 * j + q16] = f2bf(o[i][j][r] * invl);
        }
    }
    __syncthreads();

    // ---- out projection: wave w computes cols [64w, 64w+64) for all 64 tokens ----
    f32x4 acc2[4][4] = {};
    #pragma unroll
    for (int ks = 0; ks < 8; ks++) {
        bf16x8 a2[4], b2[4];
        #pragma unroll
        for (int i = 0; i < 4; i++)
            a2[i] = *(const bf16x8*)&ost[(16 * i + q16) * 264 + ks * 32 + g * 8];
        #pragma unroll
        for (int j = 0; j < 4; j++)
            b2[j] = *(const bf16x8*)&outwb[(size_t)(w * 64 + 16 * j + q16) * 256 + ks * 32 + g * 8];
        #pragma unroll
        for (int i = 0; i < 4; i++)
            #pragma unroll
            for (int j = 0; j < 4; j++)
                acc2[i][j] = __builtin_amdgcn_mfma_f32_16x16x32_bf16(a2[i], b2[j], acc2[i][j], 0, 0, 0);
    }

    // ---- gated residual + f32 store ----
    float gates[4];
    #pragma unroll
    for (int j = 0; j < 4; j++) gates[j] = c[b * 768 + 512 + w * 64 + 16 * j + q16];
    #pragma unroll
    for (int i = 0; i < 4; i++) {
        #pragma unroll
        for (int r = 0; r < 4; r++) {
            const int row = 16 * i + 4 * g + r;
            const size_t tok = tokof(row);
            float* op = out + tok * 256 + w * 64 + q16;
            const float* xp = x + tok * 256 + w * 64 + q16;
            #pragma unroll
            for (int j = 0; j < 4; j++)
                op[16 * j] = xp[16 * j] + gates[j] * acc2[i][j][r];
        }
    }
}

extern "C" void kernel_launch(void* const* d_in, const int* in_sizes, int n_in,
                              void* d_out, int out_size, void* d_ws, size_t ws_size,
                              hipStream_t stream) {
    const float* x          = (const float*)d_in[0];
    const float* cond       = (const float*)d_in[2];
    const float* norm_scale = (const float*)d_in[3];
    const float* mod_w      = (const float*)d_in[4];
    const float* mod_b      = (const float*)d_in[5];
    const float* qkv_w      = (const float*)d_in[6];
    const float* attn_scale = (const float*)d_in[7];
    const float* out_w      = (const float*)d_in[8];

    char* ws = (char*)d_ws;
    float* c               = (float*)ws;                               // 6 KB
    unsigned short* xnb    = (unsigned short*)(ws + 8192);             // 67 MB
    unsigned short* qkvwb  = (unsigned short*)(ws + 8192 + 67108864);  // 384 KB
    unsigned short* outwb  = (unsigned short*)(ws + 8192 + 67108864 + 393216);   // 128 KB
    unsigned short* qkv    = (unsigned short*)(ws + 8192 + 67108864 + 524288);   // 201 MB
    float* out             = (float*)d_out;

    hipLaunchKernelGGL(k_mod,  dim3(384),   dim3(256), 0, stream, cond, mod_w, mod_b, c);
    hipLaunchKernelGGL(k_prep, dim3(33024), dim3(256), 0, stream,
                       x, c, norm_scale, qkv_w, out_w, xnb, qkvwb, outwb);
    hipLaunchKernelGGL(k_qkv_mfma, dim3(6144), dim3(256), 0, stream, xnb, qkvwb, attn_scale, qkv);
    hipLaunchKernelGGL(k_attn_out, dim3(2048), dim3(256), 0, stream, qkv, outwb, x, c, out);
}

// Round 7
// 286.175 us; speedup vs baseline: 1.3560x; 1.0443x over previous
//
#include <hip/hip_runtime.h>
#include <hip/hip_bf16.h>
#include <cstdint>

#define DEV __device__ __forceinline__

constexpr int D_   = 256;
constexpr int CF_  = 768;
constexpr int NTOK = 131072;             // 2*256*256
constexpr int SHIFT = 4;
constexpr float EPS_ = 1e-6f;

typedef short bf16x8 __attribute__((ext_vector_type(8)));
typedef float f32x4  __attribute__((ext_vector_type(4)));

DEV float bf2f(unsigned short u) {
    unsigned v = ((unsigned)u) << 16;
    return __builtin_bit_cast(float, v);
}
DEV unsigned short f2bf(float f) {
    unsigned u = __builtin_bit_cast(unsigned, f);
    unsigned r = (u + 0x7fffu + ((u >> 16) & 1u)) >> 16;
    return (unsigned short)r;
}
DEV unsigned cvtpk(float lo, float hi) {      // packed f32->bf16 RNE (no builtin on gfx950)
    unsigned r;
    asm("v_cvt_pk_bf16_f32 %0, %1, %2" : "=v"(r) : "v"(lo), "v"(hi));
    return r;
}
DEV float wave_sum(float v) {
    #pragma unroll
    for (int o = 32; o; o >>= 1) v += __shfl_xor(v, o, 64);
    return v;
}
DEV void gl_lds16(const void* g, void* l) {
    __builtin_amdgcn_global_load_lds(
        (const __attribute__((address_space(1))) void*)g,
        (__attribute__((address_space(3))) void*)l, 16, 0, 0);
}

// ---------------- kernel 1: modulation c = silu(cond) @ mod_w.T + mod_b ----------------
__global__ void k_mod(const float* __restrict__ cond, const float* __restrict__ mod_w,
                      const float* __restrict__ mod_b, float* __restrict__ c) {
    int wv = threadIdx.x >> 6, lane = threadIdx.x & 63;
    int idx = blockIdx.x * 4 + wv;
    int b = idx / (3 * D_), j = idx % (3 * D_);
    float acc = 0.f;
    for (int k = lane; k < CF_; k += 64) {
        float cv = cond[b * CF_ + k];
        float s = cv / (1.f + expf(-cv));
        acc += s * mod_w[(size_t)j * CF_ + k];
    }
    acc = wave_sum(acc);
    if (lane == 0) c[b * (3 * D_) + j] = acc + mod_b[j];
}

// ---------------- kernel 2: merged prep: xn bf16 (RMS+mod) AND weight casts ----------------
__global__ void k_prep(const float* __restrict__ x, const float* __restrict__ c,
                       const float* __restrict__ norm_scale,
                       const float* __restrict__ qkv_w, const float* __restrict__ out_w,
                       unsigned short* __restrict__ xnb,
                       unsigned short* __restrict__ qkvwb, unsigned short* __restrict__ outwb) {
    if (blockIdx.x < 32768) {
        int wv = threadIdx.x >> 6, lane = threadIdx.x & 63;
        int t = blockIdx.x * 4 + wv;
        int b = t >> 16;
        const float* xp = x + (size_t)t * D_ + lane * 4;
        float4 v = *(const float4*)xp;
        float s = v.x * v.x + v.y * v.y + v.z * v.z + v.w * v.w;
        s = wave_sum(s);
        float rinv = rsqrtf(s * (1.f / D_) + EPS_);
        float4 sc = *(const float4*)(c + b * 768 + 256 + lane * 4);
        float4 sh = *(const float4*)(c + b * 768 + lane * 4);
        float4 ns = *(const float4*)(norm_scale + lane * 4);
        float y0 = v.x * rinv * ((1.f + sc.x) * ns.x) + sh.x;
        float y1 = v.y * rinv * ((1.f + sc.y) * ns.y) + sh.y;
        float y2 = v.z * rinv * ((1.f + sc.z) * ns.z) + sh.z;
        float y3 = v.w * rinv * ((1.f + sc.w) * ns.w) + sh.w;
        uint2 p;
        p.x = cvtpk(y0, y1);
        p.y = cvtpk(y2, y3);
        *(uint2*)(xnb + (size_t)t * D_ + lane * 4) = p;
    } else {
        int i = (blockIdx.x - 32768) * 256 + threadIdx.x;
        const float* src; unsigned short* dst; int off;
        if (i < 49152) { src = qkv_w; dst = qkvwb; off = i * 4; }
        else           { src = out_w; dst = outwb; off = (i - 49152) * 4; }
        float4 v = *(const float4*)(src + off);
        uint2 p;
        p.x = cvtpk(v.x, v.y);
        p.y = cvtpk(v.z, v.w);
        *(uint2*)(dst + off) = p;
    }
}

// ---------------- kernel 3: QKV GEMM via MFMA, 2-phase pipelined, fused qk-norm+RoPE ----
// XCD-chunked, n-tile-innermost swizzle (L2 A-panel reuse). Double-buffered LDS:
// each K-step issues next-tile global_load_lds BEFORE ds_read+MFMA of current;
// ONE __syncthreads (vmcnt0+barrier) per step — loads in flight under compute.
__global__ __launch_bounds__(256) void k_qkv_mfma(const unsigned short* __restrict__ xnb,
                                                  const unsigned short* __restrict__ wb,
                                                  const float* __restrict__ attn_scale,
                                                  unsigned short* __restrict__ qkv) {
    __shared__ unsigned short As[2][128 * 32];
    __shared__ unsigned short Bs[2][128 * 32];
    const int t = threadIdx.x, l = t & 63, w = t >> 6;
    const int bid = blockIdx.x;
    const int lid = (bid & 7) * 768 + (bid >> 3);    // 6144 blocks, 8 XCD chunks of 768
    const int m0 = (lid / 6) * 128;
    const int nt = lid % 6;
    const int n0 = nt * 128;
    const int wm = w >> 1, wn = w & 1;
    f32x4 acc[4][4] = {};

    const int srow = w * 32 + (l >> 2);
    const int scol = (l & 3) * 8;
    const unsigned short* aA = xnb + (size_t)(m0 + srow) * 256 + scol;
    const unsigned short* aB = wb  + (size_t)(n0 + srow) * 256 + scol;

    auto stage = [&](int buf, int k0) {
        gl_lds16(aA + k0,            &As[buf][(w * 2 + 0) * 512]);
        gl_lds16(aA + k0 + 16 * 256, &As[buf][(w * 2 + 1) * 512]);
        gl_lds16(aB + k0,            &Bs[buf][(w * 2 + 0) * 512]);
        gl_lds16(aB + k0 + 16 * 256, &Bs[buf][(w * 2 + 1) * 512]);
    };

    stage(0, 0);
    __syncthreads();
    int cur = 0;
    #pragma unroll
    for (int step = 0; step < 8; ++step) {
        if (step < 7) stage(cur ^ 1, (step + 1) * 32);   // prefetch next tile
        bf16x8 af[4], bff[4];
        #pragma unroll
        for (int i = 0; i < 4; i++) {
            af[i]  = *(const bf16x8*)&As[cur][(wm * 64 + i * 16 + (l & 15)) * 32 + (l >> 4) * 8];
            bff[i] = *(const bf16x8*)&Bs[cur][(wn * 64 + i * 16 + (l & 15)) * 32 + (l >> 4) * 8];
        }
        #pragma unroll
        for (int i = 0; i < 4; i++)
            #pragma unroll
            for (int j = 0; j < 4; j++)
                acc[i][j] = __builtin_amdgcn_mfma_f32_16x16x32_bf16(af[i], bff[j], acc[i][j], 0, 0, 0);
        __syncthreads();          // single vmcnt(0)+barrier per K-step
        cur ^= 1;
    }

    const int row0 = m0 + wm * 64 + (l >> 4) * 4;
    const int col0 = n0 + wn * 64 + (l & 15);
    const int q16 = l & 15;

    if (nt < 4) {
        // q (nt=0,1) or k (nt=2,3): fused L2-norm * sqrt(scale) + RoPE
        const int head = (nt * 2 + wn) & 3;
        const float ssc = sqrtf(attn_scale[head]);
        const float freq = expf(1.14472988584940017f + (float)((q16 & 7) * 4 + head) * 0.07195578545544534f);
        #pragma unroll
        for (int i = 0; i < 4; i++) {
            #pragma unroll
            for (int rg = 0; rg < 4; rg++) {
                float ss = acc[i][0][rg] * acc[i][0][rg] + acc[i][1][rg] * acc[i][1][rg]
                         + acc[i][2][rg] * acc[i][2][rg] + acc[i][3][rg] * acc[i][3][rg];
                ss += __shfl_xor(ss, 1, 64);
                ss += __shfl_xor(ss, 2, 64);
                ss += __shfl_xor(ss, 4, 64);
                ss += __shfl_xor(ss, 8, 64);
                const float rinv = ssc * rsqrtf(ss + EPS_);
                const int row = row0 + i * 16 + rg;
                const int oy = (row >> 8) & 255, ox = row & 255;
                const float ph = -1.f + (float)oy * (2.f / 255.f);
                const float pw = -1.f + (float)ox * (2.f / 255.f);
                const float th = ((q16 < 8) ? ph : pw) * freq;
                float sn, cs;
                __sincosf(th, &sn, &cs);       // hw v_sin/v_cos, |th|<32
                const float n0v = acc[i][0][rg] * rinv;
                const float n1v = acc[i][1][rg] * rinv;
                const float n2v = acc[i][2][rg] * rinv;
                const float n3v = acc[i][3][rg] * rinv;
                unsigned short* qp = qkv + (size_t)row * 768 + col0;
                qp[0]  = f2bf(n0v * cs - n1v * sn);
                qp[16] = f2bf(n1v * cs + n0v * sn);
                qp[32] = f2bf(n2v);
                qp[48] = f2bf(n3v);
            }
        }
    } else {
        #pragma unroll
        for (int i = 0; i < 4; i++)
            #pragma unroll
            for (int j = 0; j < 4; j++) {
                #pragma unroll
                for (int rg = 0; rg < 4; rg++)
                    qkv[(size_t)(row0 + i * 16 + rg) * 768 + col0 + j * 16] = f2bf(acc[i][j][rg]);
            }
    }
}

// ---------------- kernel 4: fused window attention + out-projection + gated residual ----
// Block = 1 window, 4 waves = 4 heads. S^T = mfma(K,Q); softmax in-register; P goes
// in-register to PV A-fragments via cvt_pk_bf16 + shfl (no P LDS). V^T staged per wave
// (36.9 KB); after PV the same LDS is reused as the o-stage [64][264] for the out GEMM.
__global__ __launch_bounds__(256) void k_attn_out(const unsigned short* __restrict__ qkv,
                                                  const unsigned short* __restrict__ outwb,
                                                  const float* __restrict__ x,
                                                  const float* __restrict__ c,
                                                  float* __restrict__ out) {
    __shared__ unsigned short Mem[4 * 64 * 72];    // per-wave V^T; reused as ostage[64][264]
    __shared__ float Ls[4][64];
    const int w = threadIdx.x >> 6, l = threadIdx.x & 63;
    const int bid = blockIdx.x;
    const int lid = (bid & 7) * 256 + (bid >> 3);  // XCD-contiguous windows
    const int wx = lid & 31, wy = (lid >> 5) & 31, b = lid >> 10;
    const int head = w;
    const int g = l >> 4, q16 = l & 15;
    unsigned short* Vt = &Mem[w * 4608];

    auto tokof = [&](int p) -> size_t {
        int oy = (wy * 8 + (p >> 3) - SHIFT) & 255;
        int ox = (wx * 8 + (p & 7) - SHIFT) & 255;
        return (size_t)b * 65536 + (size_t)oy * 256 + ox;
    };

    // ---- stage V^T (this wave's head): Vt[d][key] ----
    {
        const unsigned short* vp = qkv + tokof(l) * 768 + 512 + head * 64;
        uint4 vr[8];
        #pragma unroll
        for (int i = 0; i < 8; i++) vr[i] = *(const uint4*)(vp + i * 8);
        #pragma unroll
        for (int i = 0; i < 8; i++) {
            unsigned wd[4] = {vr[i].x, vr[i].y, vr[i].z, vr[i].w};
            #pragma unroll
            for (int cc = 0; cc < 4; cc++) {
                Vt[(i * 8 + cc * 2 + 0) * 72 + l] = (unsigned short)(wd[cc] & 0xffff);
                Vt[(i * 8 + cc * 2 + 1) * 72 + l] = (unsigned short)(wd[cc] >> 16);
            }
        }
    }

    // ---- K (A) and Q (B) fragments direct from global ----
    bf16x8 af[4][2], bq[4][2];
    #pragma unroll
    for (int i = 0; i < 4; i++) {
        size_t tk = tokof(i * 16 + q16);
        const unsigned short* kp = qkv + tk * 768 + 256 + head * 64 + g * 8;
        af[i][0] = *(const bf16x8*)(kp);
        af[i][1] = *(const bf16x8*)(kp + 32);
        const unsigned short* qp = qkv + tk * 768 + head * 64 + g * 8;
        bq[i][0] = *(const bf16x8*)(qp);
        bq[i][1] = *(const bf16x8*)(qp + 32);
    }

    // ---- S^T = K @ Q^T: st[i][j][r] = S[key=16i+4g+r][query=16j+q16] ----
    f32x4 st[4][4] = {};
    #pragma unroll
    for (int ks = 0; ks < 2; ks++)
        #pragma unroll
        for (int i = 0; i < 4; i++)
            #pragma unroll
            for (int j = 0; j < 4; j++)
                st[i][j] = __builtin_amdgcn_mfma_f32_16x16x32_bf16(af[i][ks], bq[j][ks], st[i][j], 0, 0, 0);

    // ---- boundary-window mask ----
    const bool topw = (wy == 0), leftw = (wx == 0);
    if (topw || leftw) {
        #pragma unroll
        for (int j = 0; j < 4; j++) {
            int query = 16 * j + q16;
            bool qa = ((query >> 3) < 4), qlf = ((query & 7) < 4);
            #pragma unroll
            for (int i = 0; i < 4; i++)
                #pragma unroll
                for (int r = 0; r < 4; r++) {
                    int key = 16 * i + 4 * g + r;
                    bool ok = (!leftw || (qlf == ((key & 7) < 4))) &&
                              (!topw || (qa == ((key >> 3) < 4)));
                    if (!ok) st[i][j][r] = -1e9f;
                }
        }
    }

    // ---- softmax over keys (per query col) ----
    #pragma unroll
    for (int j = 0; j < 4; j++) {
        float m = -1e30f;
        #pragma unroll
        for (int i = 0; i < 4; i++)
            #pragma unroll
            for (int r = 0; r < 4; r++) m = fmaxf(m, st[i][j][r]);
        m = fmaxf(m, __shfl_xor(m, 16, 64));
        m = fmaxf(m, __shfl_xor(m, 32, 64));
        float s = 0.f;
        #pragma unroll
        for (int i = 0; i < 4; i++)
            #pragma unroll
            for (int r = 0; r < 4; r++) {
                float p = __expf(st[i][j][r] - m);
                st[i][j][r] = p;
                s += p;
            }
        s += __shfl_xor(s, 16, 64);
        s += __shfl_xor(s, 32, 64);
        if (g == 0) Ls[w][16 * j + q16] = s;
    }
    __syncthreads();    // Vt fully staged (also orders later Mem reuse)

    // ---- PV with in-register P transpose (cvt_pk + shfl; no P LDS) ----
    bf16x8 vb[4][2];
    #pragma unroll
    for (int j = 0; j < 4; j++) {
        vb[j][0] = *(const bf16x8*)&Vt[(16 * j + q16) * 72 + g * 8];
        vb[j][1] = *(const bf16x8*)&Vt[(16 * j + q16) * 72 + 32 + g * 8];
    }
    const int ghi = g >> 1;
    const int srcl0 = ((2 * (g & 1)) & 3) * 16 + q16;
    const int srcl1 = ((2 * (g & 1) + 1) & 3) * 16 + q16;
    f32x4 o[4][4] = {};
    #pragma unroll
    for (int qb = 0; qb < 4; qb++) {
        unsigned pk[8];
        #pragma unroll
        for (int ih = 0; ih < 4; ih++) {
            pk[2 * ih]     = cvtpk(st[ih][qb][0], st[ih][qb][1]);
            pk[2 * ih + 1] = cvtpk(st[ih][qb][2], st[ih][qb][3]);
        }
        unsigned pw[8];
        #pragma unroll
        for (int ks = 0; ks < 2; ks++) {
            #pragma unroll
            for (int wd = 0; wd < 4; wd++) {
                const int srcl = (wd < 2) ? srcl0 : srcl1;
                unsigned va  = (unsigned)__shfl((int)pk[4 * ks + (wd & 1)], srcl, 64);
                unsigned vbb = (unsigned)__shfl((int)pk[4 * ks + 2 + (wd & 1)], srcl, 64);
                pw[ks * 4 + wd] = ghi ? vbb : va;
            }
        }
        uint4 paw0 = {pw[0], pw[1], pw[2], pw[3]};
        uint4 paw1 = {pw[4], pw[5], pw[6], pw[7]};
        bf16x8 paA = __builtin_bit_cast(bf16x8, paw0);
        bf16x8 paB = __builtin_bit_cast(bf16x8, paw1);
        #pragma unroll
        for (int j = 0; j < 4; j++) {
            o[qb][j] = __builtin_amdgcn_mfma_f32_16x16x32_bf16(paA, vb[j][0], o[qb][j], 0, 0, 0);
            o[qb][j] = __builtin_amdgcn_mfma_f32_16x16x32_bf16(paB, vb[j][1], o[qb][j], 0, 0, 0);
        }
    }

    // ---- scale by 1/l, stage O bf16 into LDS [64][264] (reusing Vt memory) ----
    __syncthreads();    // all Vt reads done before overwrite
    unsigned short* ost = Mem;
    #pragma unroll
    for (int i = 0; i < 4; i++) {
        float4 lv = *(const float4*)&Ls[w][16 * i + 4 * g];
        float lvr[4] = {lv.x, lv.y, lv.z, lv.w};
        #pragma unroll
        for (int r = 0; r < 4; r++) {
            const float invl = 1.f / lvr[r];
            const int row = 16 * i + 4 * g + r;
            #pragma unroll
            for (int j = 0; j < 4; j++)
                ost[row * 264 + head * 64 + 16 * j + q16] = f2bf(o[i][j][r] * invl);
        }
    }
    __syncthreads();

    // ---- out projection: wave w computes cols [64w, 64w+64) for all 64 tokens ----
    f32x4 acc2[4][4] = {};
    #pragma unroll
    for (int ks = 0; ks < 8; ks++) {
        bf16x8 a2[4], b2[4];
        #pragma unroll
        for (int i = 0; i < 4; i++)
            a2[i] = *(const bf16x8*)&ost[(16 * i + q16) * 264 + ks * 32 + g * 8];
        #pragma unroll
        for (int j = 0; j < 4; j++)
            b2[j] = *(const bf16x8*)&outwb[(size_t)(w * 64 + 16 * j + q16) * 256 + ks * 32 + g * 8];
        #pragma unroll
        for (int i = 0; i < 4; i++)
            #pragma unroll
            for (int j = 0; j < 4; j++)
                acc2[i][j] = __builtin_amdgcn_mfma_f32_16x16x32_bf16(a2[i], b2[j], acc2[i][j], 0, 0, 0);
    }

    // ---- gated residual + f32 store ----
    float gates[4];
    #pragma unroll
    for (int j = 0; j < 4; j++) gates[j] = c[b * 768 + 512 + w * 64 + 16 * j + q16];
    #pragma unroll
    for (int i = 0; i < 4; i++) {
        #pragma unroll
        for (int r = 0; r < 4; r++) {
            const int row = 16 * i + 4 * g + r;
            const size_t tok = tokof(row);
            float* op = out + tok * 256 + w * 64 + q16;
            const float* xp = x + tok * 256 + w * 64 + q16;
            #pragma unroll
            for (int j = 0; j < 4; j++)
                op[16 * j] = xp[16 * j] + gates[j] * acc2[i][j][r];
        }
    }
}

extern "C" void kernel_launch(void* const* d_in, const int* in_sizes, int n_in,
                              void* d_out, int out_size, void* d_ws, size_t ws_size,
                              hipStream_t stream) {
    const float* x          = (const float*)d_in[0];
    const float* cond       = (const float*)d_in[2];
    const float* norm_scale = (const float*)d_in[3];
    const float* mod_w      = (const float*)d_in[4];
    const float* mod_b      = (const float*)d_in[5];
    const float* qkv_w      = (const float*)d_in[6];
    const float* attn_scale = (const float*)d_in[7];
    const float* out_w      = (const float*)d_in[8];

    char* ws = (char*)d_ws;
    float* c               = (float*)ws;                               // 6 KB
    unsigned short* xnb    = (unsigned short*)(ws + 8192);             // 67 MB
    unsigned short* qkvwb  = (unsigned short*)(ws + 8192 + 67108864);  // 384 KB
    unsigned short* outwb  = (unsigned short*)(ws + 8192 + 67108864 + 393216);   // 128 KB
    unsigned short* qkv    = (unsigned short*)(ws + 8192 + 67108864 + 524288);   // 201 MB
    float* out             = (float*)d_out;

    hipLaunchKernelGGL(k_mod,  dim3(384),   dim3(256), 0, stream, cond, mod_w, mod_b, c);
    hipLaunchKernelGGL(k_prep, dim3(33024), dim3(256), 0, stream,
                       x, c, norm_scale, qkv_w, out_w, xnb, qkvwb, outwb);
    hipLaunchKernelGGL(k_qkv_mfma, dim3(6144), dim3(256), 0, stream, xnb, qkvwb, attn_scale, qkv);
    hipLaunchKernelGGL(k_attn_out, dim3(2048), dim3(256), 0, stream, qkv, outwb, x, c, out);
}

// Round 8
// 260.922 us; speedup vs baseline: 1.4873x; 1.0968x over previous
//
#include <hip/hip_runtime.h>
#include <hip/hip_bf16.h>
#include <cstdint>

#define DEV __device__ __forceinline__

constexpr int D_   = 256;
constexpr int CF_  = 768;
constexpr int NTOK = 131072;             // 2*256*256
constexpr int SHIFT = 4;
constexpr float EPS_ = 1e-6f;

typedef short bf16x8 __attribute__((ext_vector_type(8)));
typedef float f32x4  __attribute__((ext_vector_type(4)));

DEV float bf2f(unsigned short u) {
    unsigned v = ((unsigned)u) << 16;
    return __builtin_bit_cast(float, v);
}
DEV unsigned short f2bf(float f) {
    unsigned u = __builtin_bit_cast(unsigned, f);
    unsigned r = (u + 0x7fffu + ((u >> 16) & 1u)) >> 16;
    return (unsigned short)r;
}
DEV unsigned cvtpk(float lo, float hi) {      // packed f32->bf16 RNE (no builtin on gfx950)
    unsigned r;
    asm("v_cvt_pk_bf16_f32 %0, %1, %2" : "=v"(r) : "v"(lo), "v"(hi));
    return r;
}
DEV float wave_sum(float v) {
    #pragma unroll
    for (int o = 32; o; o >>= 1) v += __shfl_xor(v, o, 64);
    return v;
}
DEV void gl_lds16(const void* g, void* l) {
    __builtin_amdgcn_global_load_lds(
        (const __attribute__((address_space(1))) void*)g,
        (__attribute__((address_space(3))) void*)l, 16, 0, 0);
}

// ---------------- kernel 1: modulation c = silu(cond) @ mod_w.T + mod_b ----------------
__global__ void k_mod(const float* __restrict__ cond, const float* __restrict__ mod_w,
                      const float* __restrict__ mod_b, float* __restrict__ c) {
    int wv = threadIdx.x >> 6, lane = threadIdx.x & 63;
    int idx = blockIdx.x * 4 + wv;
    int b = idx / (3 * D_), j = idx % (3 * D_);
    float acc = 0.f;
    for (int k = lane; k < CF_; k += 64) {
        float cv = cond[b * CF_ + k];
        float s = cv / (1.f + expf(-cv));
        acc += s * mod_w[(size_t)j * CF_ + k];
    }
    acc = wave_sum(acc);
    if (lane == 0) c[b * (3 * D_) + j] = acc + mod_b[j];
}

// ---------------- kernel 2: merged prep: xn bf16 (RMS+mod) AND weight casts ----------------
__global__ void k_prep(const float* __restrict__ x, const float* __restrict__ c,
                       const float* __restrict__ norm_scale,
                       const float* __restrict__ qkv_w, const float* __restrict__ out_w,
                       unsigned short* __restrict__ xnb,
                       unsigned short* __restrict__ qkvwb, unsigned short* __restrict__ outwb) {
    if (blockIdx.x < 32768) {
        int wv = threadIdx.x >> 6, lane = threadIdx.x & 63;
        int t = blockIdx.x * 4 + wv;
        int b = t >> 16;
        const float* xp = x + (size_t)t * D_ + lane * 4;
        float4 v = *(const float4*)xp;
        float s = v.x * v.x + v.y * v.y + v.z * v.z + v.w * v.w;
        s = wave_sum(s);
        float rinv = rsqrtf(s * (1.f / D_) + EPS_);
        float4 sc = *(const float4*)(c + b * 768 + 256 + lane * 4);
        float4 sh = *(const float4*)(c + b * 768 + lane * 4);
        float4 ns = *(const float4*)(norm_scale + lane * 4);
        float y0 = v.x * rinv * ((1.f + sc.x) * ns.x) + sh.x;
        float y1 = v.y * rinv * ((1.f + sc.y) * ns.y) + sh.y;
        float y2 = v.z * rinv * ((1.f + sc.z) * ns.z) + sh.z;
        float y3 = v.w * rinv * ((1.f + sc.w) * ns.w) + sh.w;
        uint2 p;
        p.x = cvtpk(y0, y1);
        p.y = cvtpk(y2, y3);
        *(uint2*)(xnb + (size_t)t * D_ + lane * 4) = p;
    } else {
        int i = (blockIdx.x - 32768) * 256 + threadIdx.x;
        const float* src; unsigned short* dst; int off;
        if (i < 49152) { src = qkv_w; dst = qkvwb; off = i * 4; }
        else           { src = out_w; dst = outwb; off = (i - 49152) * 4; }
        float4 v = *(const float4*)(src + off);
        uint2 p;
        p.x = cvtpk(v.x, v.y);
        p.y = cvtpk(v.z, v.w);
        *(uint2*)(dst + off) = p;
    }
}

// ---------------- kernel 3: QKV GEMM, 2-phase pipelined, swizzled LDS, wide stores ----
// XCD-chunked n-innermost swizzle (L2 A-panel reuse). Double-buffered LDS with one
// barrier per K-step. LDS 16B-slot XOR-swizzle (slot ^= (row>>1)&3) applied on the
// GLOBAL source address (gl_lds dest linear) and on the ds_read slot -> 2-way banks.
// Epilogue transposes through LDS [128][136] so global stores are dwordx4-coalesced.
__global__ __launch_bounds__(256) void k_qkv_mfma(const unsigned short* __restrict__ xnb,
                                                  const unsigned short* __restrict__ wb,
                                                  const float* __restrict__ attn_scale,
                                                  unsigned short* __restrict__ qkv) {
    __shared__ unsigned short SM[17408];           // loop: As[2][4096]+Bs[2][4096]; epi: [128][136]
    unsigned short* As = SM;                       // As[buf] = SM + buf*4096
    unsigned short* Bs = SM + 8192;
    const int t = threadIdx.x, l = t & 63, w = t >> 6;
    const int bid = blockIdx.x;
    const int lid = (bid & 7) * 768 + (bid >> 3);  // 6144 blocks, 8 XCD chunks of 768
    const int m0 = (lid / 6) * 128;
    const int nt = lid % 6;
    const int n0 = nt * 128;
    const int wm = w >> 1, wn = w & 1;
    f32x4 acc[4][4] = {};

    const int srow = w * 32 + (l >> 2);
    const int scol = (((l & 3) ^ ((l >> 3) & 3)) * 8);   // swizzled source slot
    const unsigned short* aA = xnb + (size_t)(m0 + srow) * 256 + scol;
    const unsigned short* aB = wb  + (size_t)(n0 + srow) * 256 + scol;

    auto stage = [&](int buf, int k0) {
        gl_lds16(aA + k0,            &As[buf * 4096 + (w * 2 + 0) * 512]);
        gl_lds16(aA + k0 + 16 * 256, &As[buf * 4096 + (w * 2 + 1) * 512]);
        gl_lds16(aB + k0,            &Bs[buf * 4096 + (w * 2 + 0) * 512]);
        gl_lds16(aB + k0 + 16 * 256, &Bs[buf * 4096 + (w * 2 + 1) * 512]);
    };

    const int q16 = l & 15, g = l >> 4;
    const int rslot = (g ^ ((q16 >> 1) & 3)) * 8;        // swizzled read slot

    stage(0, 0);
    __syncthreads();
    int cur = 0;
    #pragma unroll
    for (int step = 0; step < 8; ++step) {
        if (step < 7) stage(cur ^ 1, (step + 1) * 32);   // prefetch next tile (in flight under MFMA)
        bf16x8 af[4], bff[4];
        #pragma unroll
        for (int i = 0; i < 4; i++) {
            af[i]  = *(const bf16x8*)&As[cur * 4096 + (wm * 64 + i * 16 + q16) * 32 + rslot];
            bff[i] = *(const bf16x8*)&Bs[cur * 4096 + (wn * 64 + i * 16 + q16) * 32 + rslot];
        }
        #pragma unroll
        for (int i = 0; i < 4; i++)
            #pragma unroll
            for (int j = 0; j < 4; j++)
                acc[i][j] = __builtin_amdgcn_mfma_f32_16x16x32_bf16(af[i], bff[j], acc[i][j], 0, 0, 0);
        __syncthreads();          // vmcnt(0)+barrier per K-step
        cur ^= 1;
    }

    // ---- epilogue: transform in-register, stage to LDS [128][136], wide coalesced stores ----
    const int rl0 = wm * 64 + g * 4;       // local row base (tile coords)
    const int cl0 = wn * 64 + q16;         // local col base

    if (nt < 4) {
        // q (nt=0,1) or k (nt=2,3): fused L2-norm * sqrt(scale) + RoPE
        const int head = (nt * 2 + wn) & 3;
        const float ssc = sqrtf(attn_scale[head]);
        const float freq = expf(1.14472988584940017f + (float)((q16 & 7) * 4 + head) * 0.07195578545544534f);
        #pragma unroll
        for (int i = 0; i < 4; i++) {
            #pragma unroll
            for (int rg = 0; rg < 4; rg++) {
                float ss = acc[i][0][rg] * acc[i][0][rg] + acc[i][1][rg] * acc[i][1][rg]
                         + acc[i][2][rg] * acc[i][2][rg] + acc[i][3][rg] * acc[i][3][rg];
                ss += __shfl_xor(ss, 1, 64);
                ss += __shfl_xor(ss, 2, 64);
                ss += __shfl_xor(ss, 4, 64);
                ss += __shfl_xor(ss, 8, 64);
                const float rinv = ssc * rsqrtf(ss + EPS_);
                const int rl = rl0 + i * 16 + rg;
                const int row = m0 + rl;
                const int oy = (row >> 8) & 255, ox = row & 255;
                const float ph = -1.f + (float)oy * (2.f / 255.f);
                const float pw = -1.f + (float)ox * (2.f / 255.f);
                const float th = ((q16 < 8) ? ph : pw) * freq;
                float sn, cs;
                __sincosf(th, &sn, &cs);
                const float n0v = acc[i][0][rg] * rinv;
                const float n1v = acc[i][1][rg] * rinv;
                const float n2v = acc[i][2][rg] * rinv;
                const float n3v = acc[i][3][rg] * rinv;
                SM[rl * 136 + cl0]      = f2bf(n0v * cs - n1v * sn);
                SM[rl * 136 + cl0 + 16] = f2bf(n1v * cs + n0v * sn);
                SM[rl * 136 + cl0 + 32] = f2bf(n2v);
                SM[rl * 136 + cl0 + 48] = f2bf(n3v);
            }
        }
    } else {
        #pragma unroll
        for (int i = 0; i < 4; i++)
            #pragma unroll
            for (int rg = 0; rg < 4; rg++) {
                const int rl = rl0 + i * 16 + rg;
                #pragma unroll
                for (int j = 0; j < 4; j++)
                    SM[rl * 136 + cl0 + j * 16] = f2bf(acc[i][j][rg]);
            }
    }
    __syncthreads();

    // coalesced store: thread t -> rows (t>>4)+16*it, cols (t&15)*8 .. +7
    {
        const int cr = (t & 15) * 8, rr = t >> 4;
        #pragma unroll
        for (int it = 0; it < 8; it++) {
            const int rl = rr + it * 16;
            uint4 vv = *(const uint4*)&SM[rl * 136 + cr];
            *(uint4*)(qkv + (size_t)(m0 + rl) * 768 + n0 + cr) = vv;
        }
    }
}

// ---------------- kernel 4: fused window attention + out-projection + gated residual ----
// Block = 1 window, 4 waves = 4 heads. S^T = mfma(K,Q); softmax in-register; P goes
// in-register to PV A-fragments via cvt_pk_bf16 + shfl (no P LDS). V^T staged per wave
// (36.9 KB); after PV the same LDS is reused as the o-stage [64][264] for the out GEMM.
__global__ __launch_bounds__(256) void k_attn_out(const unsigned short* __restrict__ qkv,
                                                  const unsigned short* __restrict__ outwb,
                                                  const float* __restrict__ x,
                                                  const float* __restrict__ c,
                                                  float* __restrict__ out) {
    __shared__ unsigned short Mem[4 * 64 * 72];    // per-wave V^T; reused as ostage[64][264]
    __shared__ float Ls[4][64];
    const int w = threadIdx.x >> 6, l = threadIdx.x & 63;
    const int bid = blockIdx.x;
    const int lid = (bid & 7) * 256 + (bid >> 3);  // XCD-contiguous windows
    const int wx = lid & 31, wy = (lid >> 5) & 31, b = lid >> 10;
    const int head = w;
    const int g = l >> 4, q16 = l & 15;
    unsigned short* Vt = &Mem[w * 4608];

    auto tokof = [&](int p) -> size_t {
        int oy = (wy * 8 + (p >> 3) - SHIFT) & 255;
        int ox = (wx * 8 + (p & 7) - SHIFT) & 255;
        return (size_t)b * 65536 + (size_t)oy * 256 + ox;
    };

    // ---- stage V^T (this wave's head): Vt[d][key] ----
    {
        const unsigned short* vp = qkv + tokof(l) * 768 + 512 + head * 64;
        uint4 vr[8];
        #pragma unroll
        for (int i = 0; i < 8; i++) vr[i] = *(const uint4*)(vp + i * 8);
        #pragma unroll
        for (int i = 0; i < 8; i++) {
            unsigned wd[4] = {vr[i].x, vr[i].y, vr[i].z, vr[i].w};
            #pragma unroll
            for (int cc = 0; cc < 4; cc++) {
                Vt[(i * 8 + cc * 2 + 0) * 72 + l] = (unsigned short)(wd[cc] & 0xffff);
                Vt[(i * 8 + cc * 2 + 1) * 72 + l] = (unsigned short)(wd[cc] >> 16);
            }
        }
    }

    // ---- K (A) and Q (B) fragments direct from global ----
    bf16x8 af[4][2], bq[4][2];
    #pragma unroll
    for (int i = 0; i < 4; i++) {
        size_t tk = tokof(i * 16 + q16);
        const unsigned short* kp = qkv + tk * 768 + 256 + head * 64 + g * 8;
        af[i][0] = *(const bf16x8*)(kp);
        af[i][1] = *(const bf16x8*)(kp + 32);
        const unsigned short* qp = qkv + tk * 768 + head * 64 + g * 8;
        bq[i][0] = *(const bf16x8*)(qp);
        bq[i][1] = *(const bf16x8*)(qp + 32);
    }

    // ---- S^T = K @ Q^T: st[i][j][r] = S[key=16i+4g+r][query=16j+q16] ----
    f32x4 st[4][4] = {};
    #pragma unroll
    for (int ks = 0; ks < 2; ks++)
        #pragma unroll
        for (int i = 0; i < 4; i++)
            #pragma unroll
            for (int j = 0; j < 4; j++)
                st[i][j] = __builtin_amdgcn_mfma_f32_16x16x32_bf16(af[i][ks], bq[j][ks], st[i][j], 0, 0, 0);

    // ---- boundary-window mask ----
    const bool topw = (wy == 0), leftw = (wx == 0);
    if (topw || leftw) {
        #pragma unroll
        for (int j = 0; j < 4; j++) {
            int query = 16 * j + q16;
            bool qa = ((query >> 3) < 4), qlf = ((query & 7) < 4);
            #pragma unroll
            for (int i = 0; i < 4; i++)
                #pragma unroll
                for (int r = 0; r < 4; r++) {
                    int key = 16 * i + 4 * g + r;
                    bool ok = (!leftw || (qlf == ((key & 7) < 4))) &&
                              (!topw || (qa == ((key >> 3) < 4)));
                    if (!ok) st[i][j][r] = -1e9f;
                }
        }
    }

    // ---- softmax over keys (per query col) ----
    #pragma unroll
    for (int j = 0; j < 4; j++) {
        float m = -1e30f;
        #pragma unroll
        for (int i = 0; i < 4; i++)
            #pragma unroll
            for (int r = 0; r < 4; r++) m = fmaxf(m, st[i][j][r]);
        m = fmaxf(m, __shfl_xor(m, 16, 64));
        m = fmaxf(m, __shfl_xor(m, 32, 64));
        float s = 0.f;
        #pragma unroll
        for (int i = 0; i < 4; i++)
            #pragma unroll
            for (int r = 0; r < 4; r++) {
                float p = __expf(st[i][j][r] - m);
                st[i][j][r] = p;
                s += p;
            }
        s += __shfl_xor(s, 16, 64);
        s += __shfl_xor(s, 32, 64);
        if (g == 0) Ls[w][16 * j + q16] = s;
    }
    __syncthreads();    // Vt fully staged (also orders later Mem reuse)

    // ---- PV with in-register P transpose (cvt_pk + shfl; no P LDS) ----
    bf16x8 vb[4][2];
    #pragma unroll
    for (int j = 0; j < 4; j++) {
        vb[j][0] = *(const bf16x8*)&Vt[(16 * j + q16) * 72 + g * 8];
        vb[j][1] = *(const bf16x8*)&Vt[(16 * j + q16) * 72 + 32 + g * 8];
    }
    const int ghi = g >> 1;
    const int srcl0 = ((2 * (g & 1)) & 3) * 16 + q16;
    const int srcl1 = ((2 * (g & 1) + 1) & 3) * 16 + q16;
    f32x4 o[4][4] = {};
    #pragma unroll
    for (int qb = 0; qb < 4; qb++) {
        unsigned pk[8];
        #pragma unroll
        for (int ih = 0; ih < 4; ih++) {
            pk[2 * ih]     = cvtpk(st[ih][qb][0], st[ih][qb][1]);
            pk[2 * ih + 1] = cvtpk(st[ih][qb][2], st[ih][qb][3]);
        }
        unsigned pw[8];
        #pragma unroll
        for (int ks = 0; ks < 2; ks++) {
            #pragma unroll
            for (int wd = 0; wd < 4; wd++) {
                const int srcl = (wd < 2) ? srcl0 : srcl1;
                unsigned va  = (unsigned)__shfl((int)pk[4 * ks + (wd & 1)], srcl, 64);
                unsigned vbb = (unsigned)__shfl((int)pk[4 * ks + 2 + (wd & 1)], srcl, 64);
                pw[ks * 4 + wd] = ghi ? vbb : va;
            }
        }
        uint4 paw0 = {pw[0], pw[1], pw[2], pw[3]};
        uint4 paw1 = {pw[4], pw[5], pw[6], pw[7]};
        bf16x8 paA = __builtin_bit_cast(bf16x8, paw0);
        bf16x8 paB = __builtin_bit_cast(bf16x8, paw1);
        #pragma unroll
        for (int j = 0; j < 4; j++) {
            o[qb][j] = __builtin_amdgcn_mfma_f32_16x16x32_bf16(paA, vb[j][0], o[qb][j], 0, 0, 0);
            o[qb][j] = __builtin_amdgcn_mfma_f32_16x16x32_bf16(paB, vb[j][1], o[qb][j], 0, 0, 0);
        }
    }

    // ---- scale by 1/l, stage O bf16 into LDS [64][264] (reusing Vt memory) ----
    __syncthreads();    // all Vt reads done before overwrite
    unsigned short* ost = Mem;
    #pragma unroll
    for (int i = 0; i < 4; i++) {
        float4 lv = *(const float4*)&Ls[w][16 * i + 4 * g];
        float lvr[4] = {lv.x, lv.y, lv.z, lv.w};
        #pragma unroll
        for (int r = 0; r < 4; r++) {
            const float invl = 1.f / lvr[r];
            const int row = 16 * i + 4 * g + r;
            #pragma unroll
            for (int j = 0; j < 4; j++)
                ost[row * 264 + head * 64 + 16 * j + q16] = f2bf(o[i][j][r] * invl);
        }
    }
    __syncthreads();

    // ---- out projection: wave w computes cols [64w, 64w+64) for all 64 tokens ----
    f32x4 acc2[4][4] = {};
    #pragma unroll
    for (int ks = 0; ks < 8; ks++) {
        bf16x8 a2[4], b2[4];
        #pragma unroll
        for (int i = 0; i < 4; i++)
            a2[i] = *(const bf16x8*)&ost[(16 * i + q16) * 264 + ks * 32 + g * 8];
        #pragma unroll
        for (int j = 0; j < 4; j++)
            b2[j] = *(const bf16x8*)&outwb[(size_t)(w * 64 + 16 * j + q16) * 256 + ks * 32 + g * 8];
        #pragma unroll
        for (int i = 0; i < 4; i++)
            #pragma unroll
            for (int j = 0; j < 4; j++)
                acc2[i][j] = __builtin_amdgcn_mfma_f32_16x16x32_bf16(a2[i], b2[j], acc2[i][j], 0, 0, 0);
    }

    // ---- gated residual + f32 store ----
    float gates[4];
    #pragma unroll
    for (int j = 0; j < 4; j++) gates[j] = c[b * 768 + 512 + w * 64 + 16 * j + q16];
    #pragma unroll
    for (int i = 0; i < 4; i++) {
        #pragma unroll
        for (int r = 0; r < 4; r++) {
            const int row = 16 * i + 4 * g + r;
            const size_t tok = tokof(row);
            float* op = out + tok * 256 + w * 64 + q16;
            const float* xp = x + tok * 256 + w * 64 + q16;
            #pragma unroll
            for (int j = 0; j < 4; j++)
                op[16 * j] = xp[16 * j] + gates[j] * acc2[i][j][r];
        }
    }
}

extern "C" void kernel_launch(void* const* d_in, const int* in_sizes, int n_in,
                              void* d_out, int out_size, void* d_ws, size_t ws_size,
                              hipStream_t stream) {
    const float* x          = (const float*)d_in[0];
    const float* cond       = (const float*)d_in[2];
    const float* norm_scale = (const float*)d_in[3];
    const float* mod_w      = (const float*)d_in[4];
    const float* mod_b      = (const float*)d_in[5];
    const float* qkv_w      = (const float*)d_in[6];
    const float* attn_scale = (const float*)d_in[7];
    const float* out_w      = (const float*)d_in[8];

    char* ws = (char*)d_ws;
    float* c               = (float*)ws;                               // 6 KB
    unsigned short* xnb    = (unsigned short*)(ws + 8192);             // 67 MB
    unsigned short* qkvwb  = (unsigned short*)(ws + 8192 + 67108864);  // 384 KB
    unsigned short* outwb  = (unsigned short*)(ws + 8192 + 67108864 + 393216);   // 128 KB
    unsigned short* qkv    = (unsigned short*)(ws + 8192 + 67108864 + 524288);   // 201 MB
    float* out             = (float*)d_out;

    hipLaunchKernelGGL(k_mod,  dim3(384),   dim3(256), 0, stream, cond, mod_w, mod_b, c);
    hipLaunchKernelGGL(k_prep, dim3(33024), dim3(256), 0, stream,
                       x, c, norm_scale, qkv_w, out_w, xnb, qkvwb, outwb);
    hipLaunchKernelGGL(k_qkv_mfma, dim3(6144), dim3(256), 0, stream, xnb, qkvwb, attn_scale, qkv);
    hipLaunchKernelGGL(k_attn_out, dim3(2048), dim3(256), 0, stream, qkv, outwb, x, c, out);
}